// Round 6
// baseline (2658.880 us; speedup 1.0000x reference)
//
#include <hip/hip_runtime.h>
#include <hip/hip_bf16.h>

#define MAXD 32
typedef __hip_bfloat16 bf16;

__device__ __forceinline__ float bf2f(bf16 v) { return __bfloat162float(v); }
__device__ __forceinline__ float2 ldbf2(const bf16* p) {
  unsigned u = *(const unsigned*)p;
  return make_float2(__uint_as_float(u << 16), __uint_as_float(u & 0xffff0000u));
}
__device__ __forceinline__ float2 unpk(unsigned u) {
  return make_float2(__uint_as_float(u << 16), __uint_as_float(u & 0xffff0000u));
}
__device__ __forceinline__ unsigned pk2(float x, float y) {
  bf16 bx = __float2bfloat16(x), by = __float2bfloat16(y);
  unsigned short ux, uy;
  __builtin_memcpy(&ux, &bx, 2);
  __builtin_memcpy(&uy, &by, 2);
  return (unsigned)ux | ((unsigned)uy << 16);
}

struct EdgeParams {
  const int* e[6];
  int E[6];
  int ebase[6];
  int nbase[6];
};

struct VSrc {
  const float* hf; const bf16* hh;
  const float* skf; const bf16* skh;
  const int* up;
  int nprev, Ch, Cs;
};

__device__ __forceinline__ float vloadf(const VSrc& s, int i, int c) {
  if (s.up) {
    if (c >= s.Ch) return s.skf[(long)i * s.Cs + (c - s.Ch)];
    if (i >= s.nprev) {
      int j = i - s.nprev;
      int u0 = s.up[2 * j], u1 = s.up[2 * j + 1];
      return 0.5f * (s.hf[(long)u0 * s.Ch + c] + s.hf[(long)u1 * s.Ch + c]);
    }
    return s.hf[(long)i * s.Ch + c];
  }
  return s.hf[(long)i * s.Ch + c];
}

__device__ __forceinline__ float2 vloadh2(const VSrc& s, int i, int c2) {
  int c = 2 * c2;
  if (s.up) {
    if (c >= s.Ch) return ldbf2(s.skh + (long)i * s.Cs + (c - s.Ch));
    if (i >= s.nprev) {
      int j = i - s.nprev;
      int u0 = s.up[2 * j], u1 = s.up[2 * j + 1];
      float2 a = ldbf2(s.hh + (long)u0 * s.Ch + c);
      float2 b = ldbf2(s.hh + (long)u1 * s.Ch + c);
      return make_float2(0.5f * (a.x + b.x), 0.5f * (a.y + b.y));
    }
    return ldbf2(s.hh + (long)i * s.Ch + c);
  }
  return ldbf2(s.hh + (long)i * s.Ch + c);
}

// ---------------- setup kernels ----------------
__global__ void k_fill(EdgeParams p, int* __restrict__ cnt, int2* __restrict__ ell, int ET) {
  for (int idx = blockIdx.x * blockDim.x + threadIdx.x; idx < ET; idx += gridDim.x * blockDim.x) {
    int l;
    if (idx < p.ebase[1]) l = 0;
    else if (idx < p.ebase[2]) l = 1;
    else if (idx < p.ebase[3]) l = 2;
    else if (idx < p.ebase[4]) l = 3;
    else if (idx < p.ebase[5]) l = 4;
    else l = 5;
    int e = idx - p.ebase[l];
    const int* epp = p.e[l];
    int row = epp[e];
    int col = epp[p.E[l] + e];
    int g = p.nbase[l] + row;
    int slot = atomicAdd(&cnt[g], 1);
    if (slot < MAXD) ell[g * MAXD + slot].x = col;
  }
}

__global__ void k_wfill(EdgeParams p, const int* __restrict__ cnt, int2* __restrict__ ell, int NT) {
  int total = NT * MAXD;
  for (int idx = blockIdx.x * blockDim.x + threadIdx.x; idx < total; idx += gridDim.x * blockDim.x) {
    int g = idx >> 5;
    int t = idx & (MAXD - 1);
    int dg = cnt[g];
    int d = dg < MAXD ? dg : MAXD;
    if (t < d) {
      int l;
      if (g < p.nbase[1]) l = 0;
      else if (g < p.nbase[2]) l = 1;
      else if (g < p.nbase[3]) l = 2;
      else if (g < p.nbase[4]) l = 3;
      else if (g < p.nbase[5]) l = 4;
      else l = 5;
      int c = ell[idx].x;
      int dc = cnt[p.nbase[l] + c];
      float w = (dc > 0) ? -(rsqrtf((float)dg) * rsqrtf((float)dc)) : 0.0f;
      ell[idx].y = __float_as_int(w);
    }
  }
}

__global__ void k_cvt(const float* __restrict__ in, bf16* __restrict__ out, int N) {
  for (int i = blockIdx.x * blockDim.x + threadIdx.x; i < N; i += gridDim.x * blockDim.x)
    out[i] = __float2bfloat16(in[i]);
}

__global__ void k_xmat(VSrc src, bf16* __restrict__ Xh, int n, int Ctot) {
  int C2 = Ctot >> 1;
  int total = n * C2;
  for (int idx = blockIdx.x * blockDim.x + threadIdx.x; idx < total; idx += gridDim.x * blockDim.x) {
    int i = idx / C2;
    int c2 = idx - i * C2;
    float2 v = vloadh2(src, i, c2);
    *(unsigned*)(Xh + (long)i * Ctot + 2 * c2) = pk2(v.x, v.y);
  }
}

// ---------------- big-layer kernels (n >= 10242) ----------------
__global__ void k_prop(const bf16* __restrict__ Xh, float* __restrict__ T, bf16* __restrict__ Th,
                       const int* __restrict__ cnt, const int2* __restrict__ ell,
                       int nbase, int n, int C) {
  int C4 = C >> 2;
  int total = n * C4;
  for (int idx = blockIdx.x * blockDim.x + threadIdx.x; idx < total; idx += gridDim.x * blockDim.x) {
    int i = idx / C4;
    int c = (idx - i * C4) << 2;
    int g = nbase + i;
    int d = cnt[g]; if (d > MAXD) d = MAXD;
    const int2* cols = ell + (long)g * MAXD;
    float a0 = 0.f, a1 = 0.f, a2 = 0.f, a3 = 0.f;
    for (int t = 0; t < d; t += 8) {
      int ci[8]; float wj[8];
#pragma unroll
      for (int j = 0; j < 8; ++j) {
        int tt = t + j;
        int2 e = cols[(tt < d) ? tt : 0];
        ci[j] = e.x;
        wj[j] = (tt < d) ? __int_as_float(e.y) : 0.f;
      }
#pragma unroll
      for (int j = 0; j < 8; ++j) {
        uint2 raw = *(const uint2*)(Xh + (long)ci[j] * C + c);
        float2 v01 = unpk(raw.x);
        float2 v23 = unpk(raw.y);
        a0 += wj[j] * v01.x;
        a1 += wj[j] * v01.y;
        a2 += wj[j] * v23.x;
        a3 += wj[j] * v23.y;
      }
    }
    long o = (long)i * C + c;
    *(float4*)(T + o) = make_float4(a0, a1, a2, a3);
    uint2 pk; pk.x = pk2(a0, a1); pk.y = pk2(a2, a3);
    *(uint2*)(Th + o) = pk;
  }
}

template <int ROWS, int CW, int SMAX>
__global__ __launch_bounds__(256) void k_combine(
    VSrc src, const float* __restrict__ T1, const bf16* __restrict__ T1h,
    const float* __restrict__ W, const float* __restrict__ B,
    const int* __restrict__ cnt, const int2* __restrict__ ell,
    int nbase, int n, int Cin, int Cout, int doRelu,
    float* __restrict__ OUT, bf16* __restrict__ OUTh) {
  constexpr int RW = 4 / CW;
  constexpr int RPW = ROWS / RW;

  __shared__ __align__(16) float sx[4][RPW][64];
  __shared__ __align__(16) float st1[4][RPW][64];
  __shared__ __align__(16) float st2[4][RPW][64];

  int tid = threadIdx.x;
  int w = tid >> 6;
  int lane = tid & 63;
  int rg = w / CW;
  int cw = w % CW;

  int colTiles = (Cout + 63) >> 6;
  int ct = blockIdx.x % colTiles;
  int rt = blockIdx.x / colTiles;
  int r0 = rt * ROWS + rg * RPW;
  int o = ct * 64 + lane;
  int oc = (o < Cout) ? o : (Cout - 1);
  int nch = (Cin + 63) >> 6;

  float acc[RPW];
#pragma unroll
  for (int r = 0; r < RPW; ++r) acc[r] = 0.f;

  for (int cg = 0; cg < nch; cg += CW) {
    int c = cg + cw;
    bool act = c < nch;
    int k0 = c * 64;
    int kw = act ? ((Cin - k0 < 64) ? (Cin - k0) : 64) : 0;
    int k = k0 + lane;
    bool kv = act && (lane < kw);

#pragma unroll
    for (int rr = 0; rr < RPW; ++rr) {
      int i = r0 + rr;
      bool iv = i < n;
      float xv = 0.f, tv = 0.f, t2v = 0.f;
      if (kv && iv) {
        xv = vloadf(src, i, k);
        tv = T1[(long)i * Cin + k];
        int g = nbase + i;
        int d = cnt[g]; if (d > MAXD) d = MAXD;
        const int2* cols = ell + (long)g * MAXD;
        float a2 = 0.f;
        for (int t = 0; t < d; t += 8) {
          int ci[8]; float wj[8];
#pragma unroll
          for (int j = 0; j < 8; ++j) {
            int tt = t + j;
            int2 e = cols[(tt < d) ? tt : 0];
            ci[j] = e.x;
            wj[j] = (tt < d) ? __int_as_float(e.y) : 0.f;
          }
#pragma unroll
          for (int j = 0; j < 8; ++j)
            a2 += wj[j] * bf2f(T1h[(long)ci[j] * Cin + k]);
        }
        t2v = 2.f * a2 - xv;
      }
      sx[w][rr][lane] = xv;
      st1[w][rr][lane] = tv;
      st2[w][rr][lane] = t2v;
    }
    __syncthreads();

    int kw4 = kw >> 2;
    long ts = (long)Cin * Cout;
    for (int q = 0; q < kw4; ++q) {
      float w0[4], w1[4], w2[4];
#pragma unroll
      for (int j = 0; j < 4; ++j) {
        long off = (long)(k0 + q * 4 + j) * Cout + oc;
        w0[j] = W[off];
        w1[j] = W[ts + off];
        w2[j] = W[2 * ts + off];
      }
#pragma unroll
      for (int rr = 0; rr < RPW; ++rr) {
        float4 xs = ((const float4*)sx[w][rr])[q];
        float4 t1s = ((const float4*)st1[w][rr])[q];
        float4 t2s = ((const float4*)st2[w][rr])[q];
        acc[rr] += w0[0] * xs.x + w0[1] * xs.y + w0[2] * xs.z + w0[3] * xs.w;
        acc[rr] += w1[0] * t1s.x + w1[1] * t1s.y + w1[2] * t1s.z + w1[3] * t1s.w;
        acc[rr] += w2[0] * t2s.x + w2[1] * t2s.y + w2[2] * t2s.z + w2[3] * t2s.w;
      }
    }
    __syncthreads();
  }

  if constexpr (SMAX) {
    float bb = (o < Cout) ? B[o] : 0.f;
#pragma unroll
    for (int rr = 0; rr < RPW; ++rr) {
      int i = r0 + rr;
      if (i < n) {
        float v = (o < Cout) ? (acc[rr] + bb) : -1e30f;
        float m = v;
        for (int s = 32; s > 0; s >>= 1) m = fmaxf(m, __shfl_xor(m, s));
        float e = (o < Cout) ? __expf(v - m) : 0.f;
        float sum = e;
        for (int s = 32; s > 0; s >>= 1) sum += __shfl_xor(sum, s);
        if (o < Cout) OUT[(long)i * Cout + o] = e / sum;
      }
    }
  } else if constexpr (CW == 1) {
    if (o < Cout) {
      float bb = B[oc];
#pragma unroll
      for (int rr = 0; rr < RPW; ++rr) {
        int i = r0 + rr;
        if (i < n) {
          float v = acc[rr] + bb;
          if (doRelu) v = fmaxf(v, 0.f);
          long off = (long)i * Cout + o;
          OUT[off] = v;
          OUTh[off] = __float2bfloat16(v);
        }
      }
    }
  } else {
#pragma unroll
    for (int rr = 0; rr < RPW; ++rr) sx[w][rr][lane] = acc[rr];
    __syncthreads();
    if (cw == 0 && o < Cout) {
      float bb = B[oc];
#pragma unroll
      for (int rr = 0; rr < RPW; ++rr) {
        int i = r0 + rr;
        if (i < n) {
          float v = bb;
#pragma unroll
          for (int j = 0; j < CW; ++j) v += sx[rg * CW + j][rr][lane];
          if (doRelu) v = fmaxf(v, 0.f);
          long off = (long)i * Cout + o;
          OUT[off] = v;
          OUTh[off] = __float2bfloat16(v);
        }
      }
    }
  }
}

// ---------------- persistent mid-section kernel (L3..L9, n <= 2562) ----------------
#define NBLK 128

__device__ __forceinline__ void gridbar(unsigned* cnt, unsigned* gen) {
  __syncthreads();
  if (threadIdx.x == 0) {
    __threadfence();
    unsigned g = __hip_atomic_load(gen, __ATOMIC_RELAXED, __HIP_MEMORY_SCOPE_AGENT);
    unsigned a = __hip_atomic_fetch_add(cnt, 1u, __ATOMIC_ACQ_REL, __HIP_MEMORY_SCOPE_AGENT);
    if (a == (unsigned)NBLK - 1u) {
      __hip_atomic_store(cnt, 0u, __ATOMIC_RELAXED, __HIP_MEMORY_SCOPE_AGENT);
      __hip_atomic_fetch_add(gen, 1u, __ATOMIC_RELEASE, __HIP_MEMORY_SCOPE_AGENT);
    } else {
      while (__hip_atomic_load(gen, __ATOMIC_ACQUIRE, __HIP_MEMORY_SCOPE_AGENT) == g) {
        __builtin_amdgcn_s_sleep(2);
      }
    }
    __threadfence();
  }
  __syncthreads();
}

struct CoopParams {
  const float* hf[7];
  const float* skf[7];
  const int* up[7];
  int nprev[7], Ch[7], Cs[7];
  int n[7], Cin[7], Cout[7], nbase[7], relu[7];
  const float* W[7];
  const float* B[7];
  float* outf[7];
  bf16* outh[7];
};

__global__ __launch_bounds__(256) void k_coop(CoopParams P, const int* __restrict__ cnt,
                                              const int2* __restrict__ ell,
                                              float* __restrict__ xf, float* __restrict__ t1,
                                              float* __restrict__ t2,
                                              unsigned* bar, unsigned* gen) {
  int tid0 = blockIdx.x * blockDim.x + threadIdx.x;
  int stride = gridDim.x * blockDim.x;
  int lane = threadIdx.x & 63;
  int gwave = tid0 >> 6;
  int nwaves = stride >> 6;

  for (int li = 0; li < 7; ++li) {
    int n = P.n[li], Cin = P.Cin[li], Cout = P.Cout[li], nb = P.nbase[li];
    const float* X;
    if (P.up[li]) {
      const float* hf = P.hf[li];
      const float* skf = P.skf[li];
      const int* up = P.up[li];
      int nprev = P.nprev[li], Ch = P.Ch[li], Cs = P.Cs[li];
      int tot = n * Cin;
      for (int idx = tid0; idx < tot; idx += stride) {
        int i = idx / Cin, c = idx - i * Cin;
        float v;
        if (c >= Ch) v = skf[i * Cs + (c - Ch)];
        else if (i >= nprev) {
          int j = i - nprev;
          int u0 = up[2 * j], u1 = up[2 * j + 1];
          v = 0.5f * (hf[u0 * Ch + c] + hf[u1 * Ch + c]);
        } else v = hf[i * Ch + c];
        xf[idx] = v;
      }
      X = xf;
      gridbar(bar, gen);
    } else {
      X = P.hf[li];
    }
    // prop: t1 = A~ X
    int tot = n * Cin;
    for (int idx = tid0; idx < tot; idx += stride) {
      int i = idx / Cin, c = idx - i * Cin;
      int g = nb + i;
      int d = cnt[g]; if (d > MAXD) d = MAXD;
      const int2* cols = ell + (long)g * MAXD;
      float acc = 0.f;
      for (int t = 0; t < d; ++t) {
        int2 e = cols[t];
        acc += __int_as_float(e.y) * X[e.x * Cin + c];
      }
      t1[idx] = acc;
    }
    gridbar(bar, gen);
    // t2 = 2 A~ t1 - X
    for (int idx = tid0; idx < tot; idx += stride) {
      int i = idx / Cin, c = idx - i * Cin;
      int g = nb + i;
      int d = cnt[g]; if (d > MAXD) d = MAXD;
      const int2* cols = ell + (long)g * MAXD;
      float acc = 0.f;
      for (int t = 0; t < d; ++t) {
        int2 e = cols[t];
        acc += __int_as_float(e.y) * t1[e.x * Cin + c];
      }
      t2[idx] = 2.f * acc - X[idx];
    }
    gridbar(bar, gen);
    // gemm: out = relu([X|t1|t2] W + b). 6 rows/thread for W reuse; n % 6 == 0 for all layers.
    const float* W = P.W[li];
    const float* B = P.B[li];
    float* outf = P.outf[li];
    bf16* outh = P.outh[li];
    int doRelu = P.relu[li];
    long ts = (long)Cin * Cout;
    int oT = Cout >> 6;
    int ntiles = (n / 6) * oT;
    for (int tt = gwave; tt < ntiles; tt += nwaves) {
      int rb = tt / oT, ot = tt - rb * oT;
      int o = ot * 64 + lane;
      int i0 = rb * 6;
      float a[6];
      float bb = B[o];
#pragma unroll
      for (int r = 0; r < 6; ++r) a[r] = bb;
      const float* xr = X + (long)i0 * Cin;
      const float* t1r = t1 + (long)i0 * Cin;
      const float* t2r = t2 + (long)i0 * Cin;
      for (int k = 0; k < Cin; ++k) {
        long wo = (long)k * Cout + o;
        float w0 = W[wo], w1 = W[ts + wo], w2 = W[2 * ts + wo];
#pragma unroll
        for (int r = 0; r < 6; ++r) {
          long rk = (long)r * Cin + k;
          a[r] += w0 * xr[rk] + w1 * t1r[rk] + w2 * t2r[rk];
        }
      }
#pragma unroll
      for (int r = 0; r < 6; ++r) {
        float v = doRelu ? fmaxf(a[r], 0.f) : a[r];
        long off = (long)(i0 + r) * Cout + o;
        outf[off] = v;
        outh[off] = __float2bfloat16(v);
      }
    }
    if (li < 6) gridbar(bar, gen);
  }
}

// ---------------- launcher ----------------
extern "C" void kernel_launch(void* const* d_in, const int* in_sizes, int n_in,
                              void* d_out, int out_size, void* d_ws, size_t ws_size,
                              hipStream_t stream) {
  static const int NV[6] = {42, 162, 642, 2562, 10242, 40962};
  static const int NE[6] = {240, 960, 3840, 15360, 61440, 245760};
  const int NT = 54612;
  const int ET = 327600;

  EdgeParams ep;
  {
    int nb = 0, eb = 0;
    for (int l = 0; l < 6; ++l) {
      ep.e[l] = (const int*)d_in[1 + l];
      ep.E[l] = NE[l];
      ep.ebase[l] = eb;
      ep.nbase[l] = nb;
      eb += NE[l];
      nb += NV[l];
    }
  }
  const float* x0f = (const float*)d_in[0];
  const int* up[5];
  for (int i = 0; i < 5; ++i) up[i] = (const int*)d_in[7 + i];  // up2..up6
  const float *W[11], *Bb[11];
  for (int i = 0; i < 11; ++i) {
    W[i] = (const float*)d_in[12 + 2 * i];
    Bb[i] = (const float*)d_in[13 + 2 * i];
  }

  // ---- workspace carve (16B-aligned) ----
  char* p = (char*)d_ws;
  auto alloc_b = [&](size_t bytes) { void* r = (void*)p; p += (bytes + 15) & ~size_t(15); return r; };
  auto alloc_i = [&](size_t ne) { return (int*)alloc_b(ne * 4); };
  auto alloc_f = [&](size_t ne) { return (float*)alloc_b(ne * 4); };
  auto alloc_h = [&](size_t ne) { return (bf16*)alloc_b(ne * 2); };
  int* cnt = alloc_i(NT);
  unsigned* bar = (unsigned*)alloc_i(4);  // [0]=cnt, [1]=gen (contiguous after cnt)
  int2* ell = (int2*)alloc_b((size_t)NT * MAXD * 8);
  float* t1f = alloc_f((size_t)40962 * 36);
  bf16* t1h = alloc_h((size_t)40962 * 36);
  bf16* x0h = alloc_h((size_t)40962 * 4);
  bf16* xh = alloc_h((size_t)40962 * 36);       // big-layer materialized upcat source (bf16)
  float* xfc = alloc_f((size_t)2562 * 192);     // coop scratch
  float* t1c = alloc_f((size_t)2562 * 192);
  float* t2c = alloc_f((size_t)2562 * 192);
  float *af[10]; bf16 *ah[10];
  const int an[10] = {40962, 10242, 2562, 642, 162, 42, 162, 642, 2562, 10242};
  const int ac[10] = {32, 64, 128, 256, 512, 512, 256, 128, 64, 32};
  for (int i = 0; i < 10; ++i) {
    af[i] = alloc_f((size_t)an[i] * ac[i]);
    ah[i] = alloc_h((size_t)an[i] * ac[i]);
  }

  hipMemsetAsync(cnt, 0, (size_t)(NT + 4) * 4, stream);  // cnt + barrier slots
  k_fill<<<(ET + 255) / 256, 256, 0, stream>>>(ep, cnt, ell, ET);
  k_wfill<<<(NT * MAXD + 255) / 256, 256, 0, stream>>>(ep, cnt, ell, NT);
  k_cvt<<<(40962 * 4 + 255) / 256, 256, 0, stream>>>(x0f, x0h, 40962 * 4);

  auto plain = [](const float* hf, const bf16* hh, int Ch) {
    VSrc s{hf, hh, nullptr, nullptr, nullptr, 0, Ch, 0}; return s;
  };
  auto upsrc = [](const float* hf, const bf16* hh, const float* skf, const bf16* skh,
                  const int* u, int nprev, int Ch, int Cs) {
    VSrc s{hf, hh, skf, skh, u, nprev, Ch, Cs}; return s;
  };

  // ---- L1: n=40962, 4->32 (level idx 5) ----
  {
    VSrc s = plain(x0f, x0h, 4);
    k_prop<<<(40962 * 1 + 255) / 256, 256, 0, stream>>>(x0h, t1f, t1h, cnt, ell, ep.nbase[5], 40962, 4);
    k_combine<8, 1, 0><<<(40962 + 7) / 8, 256, 0, stream>>>(s, t1f, t1h, W[0], Bb[0], cnt, ell,
                                                            ep.nbase[5], 40962, 4, 32, 1, af[0], ah[0]);
  }
  // ---- L2: n=10242, 32->64 (level idx 4) ----
  {
    VSrc s = plain(af[0], ah[0], 32);
    k_prop<<<(10242 * 8 + 255) / 256, 256, 0, stream>>>(ah[0], t1f, t1h, cnt, ell, ep.nbase[4], 10242, 32);
    k_combine<8, 1, 0><<<(10242 + 7) / 8, 256, 0, stream>>>(s, t1f, t1h, W[1], Bb[1], cnt, ell,
                                                            ep.nbase[4], 10242, 32, 64, 1, af[1], ah[1]);
  }
  // ---- coop mid-section: L3..L9 ----
  {
    CoopParams P;
    auto set = [&](int j, const float* hf, const float* skf, const int* u, int nprev, int Ch,
                   int Cs, int n, int Cin, int Cout, int lvl, int relu, const float* Wp,
                   const float* Bp, float* of, bf16* oh) {
      P.hf[j] = hf; P.skf[j] = skf; P.up[j] = u; P.nprev[j] = nprev; P.Ch[j] = Ch; P.Cs[j] = Cs;
      P.n[j] = n; P.Cin[j] = Cin; P.Cout[j] = Cout; P.nbase[j] = ep.nbase[lvl]; P.relu[j] = relu;
      P.W[j] = Wp; P.B[j] = Bp; P.outf[j] = of; P.outh[j] = oh;
    };
    set(0, af[1], nullptr, nullptr, 0, 64, 0, 2562, 64, 128, 3, 1, W[2], Bb[2], af[2], ah[2]);
    set(1, af[2], nullptr, nullptr, 0, 128, 0, 642, 128, 256, 2, 1, W[3], Bb[3], af[3], ah[3]);
    set(2, af[3], nullptr, nullptr, 0, 256, 0, 162, 256, 512, 1, 1, W[4], Bb[4], af[4], ah[4]);
    set(3, af[4], nullptr, nullptr, 0, 512, 0, 42, 512, 512, 0, 1, W[5], Bb[5], af[5], ah[5]);
    set(4, af[5], af[3], up[0], 42, 512, 256, 162, 768, 256, 1, 1, W[6], Bb[6], af[6], ah[6]);
    set(5, af[6], af[2], up[1], 162, 256, 128, 642, 384, 128, 2, 1, W[7], Bb[7], af[7], ah[7]);
    set(6, af[7], af[1], up[2], 642, 128, 64, 2562, 192, 64, 3, 1, W[8], Bb[8], af[8], ah[8]);
    k_coop<<<NBLK, 256, 0, stream>>>(P, cnt, ell, xfc, t1c, t2c, bar, bar + 1);
  }
  // ---- L10: n=10242, [64|32]->32 (level idx 4) ----
  {
    VSrc s = upsrc(af[8], ah[8], af[0], ah[0], up[3], 2562, 64, 32);
    k_xmat<<<(10242 * 48 + 255) / 256, 256, 0, stream>>>(s, xh, 10242, 96);
    k_prop<<<(10242 * 24 + 255) / 256, 256, 0, stream>>>(xh, t1f, t1h, cnt, ell, ep.nbase[4], 10242, 96);
    k_combine<8, 2, 0><<<(10242 + 7) / 8, 256, 0, stream>>>(s, t1f, t1h, W[9], Bb[9], cnt, ell,
                                                            ep.nbase[4], 10242, 96, 32, 1, af[9], ah[9]);
  }
  // ---- L11: n=40962, [32|4]->37 + softmax (level idx 5) ----
  {
    VSrc s = upsrc(af[9], ah[9], x0f, x0h, up[4], 10242, 32, 4);
    k_xmat<<<(40962 * 18 + 255) / 256, 256, 0, stream>>>(s, xh, 40962, 36);
    k_prop<<<(40962 * 9 + 255) / 256, 256, 0, stream>>>(xh, t1f, t1h, cnt, ell, ep.nbase[5], 40962, 36);
    k_combine<8, 1, 1><<<(40962 + 7) / 8, 256, 0, stream>>>(s, t1f, t1h, W[10], Bb[10], cnt, ell,
                                                            ep.nbase[5], 40962, 36, 37, 0, (float*)d_out, nullptr);
  }
}

// Round 7
// 543.109 us; speedup vs baseline: 4.8957x; 4.8957x over previous
//
#include <hip/hip_runtime.h>
#include <hip/hip_bf16.h>

#define MAXD 32
typedef __hip_bfloat16 bf16;

__device__ __forceinline__ float bf2f(bf16 v) { return __bfloat162float(v); }
__device__ __forceinline__ float2 ldbf2(const bf16* p) {
  unsigned u = *(const unsigned*)p;
  return make_float2(__uint_as_float(u << 16), __uint_as_float(u & 0xffff0000u));
}
__device__ __forceinline__ float2 unpk(unsigned u) {
  return make_float2(__uint_as_float(u << 16), __uint_as_float(u & 0xffff0000u));
}
__device__ __forceinline__ unsigned pk2(float x, float y) {
  bf16 bx = __float2bfloat16(x), by = __float2bfloat16(y);
  unsigned short ux, uy;
  __builtin_memcpy(&ux, &bx, 2);
  __builtin_memcpy(&uy, &by, 2);
  return (unsigned)ux | ((unsigned)uy << 16);
}

struct EdgeParams {
  const int* e[6];
  int E[6];
  int ebase[6];
  int nbase[6];
};

struct VSrc {
  const float* hf; const bf16* hh;
  const float* skf; const bf16* skh;
  const int* up;
  int nprev, Ch, Cs;
};

__device__ __forceinline__ float vloadf(const VSrc& s, int i, int c) {
  if (s.up) {
    if (c >= s.Ch) return s.skf[(long)i * s.Cs + (c - s.Ch)];
    if (i >= s.nprev) {
      int j = i - s.nprev;
      int u0 = s.up[2 * j], u1 = s.up[2 * j + 1];
      return 0.5f * (s.hf[(long)u0 * s.Ch + c] + s.hf[(long)u1 * s.Ch + c]);
    }
    return s.hf[(long)i * s.Ch + c];
  }
  return s.hf[(long)i * s.Ch + c];
}

__device__ __forceinline__ float2 vloadh2(const VSrc& s, int i, int c2) {
  int c = 2 * c2;
  if (s.up) {
    if (c >= s.Ch) return ldbf2(s.skh + (long)i * s.Cs + (c - s.Ch));
    if (i >= s.nprev) {
      int j = i - s.nprev;
      int u0 = s.up[2 * j], u1 = s.up[2 * j + 1];
      float2 a = ldbf2(s.hh + (long)u0 * s.Ch + c);
      float2 b = ldbf2(s.hh + (long)u1 * s.Ch + c);
      return make_float2(0.5f * (a.x + b.x), 0.5f * (a.y + b.y));
    }
    return ldbf2(s.hh + (long)i * s.Ch + c);
  }
  return ldbf2(s.hh + (long)i * s.Ch + c);
}

// ---------------- setup kernels ----------------
__global__ void k_fill(EdgeParams p, int* __restrict__ cnt, int2* __restrict__ ell, int ET) {
  for (int idx = blockIdx.x * blockDim.x + threadIdx.x; idx < ET; idx += gridDim.x * blockDim.x) {
    int l;
    if (idx < p.ebase[1]) l = 0;
    else if (idx < p.ebase[2]) l = 1;
    else if (idx < p.ebase[3]) l = 2;
    else if (idx < p.ebase[4]) l = 3;
    else if (idx < p.ebase[5]) l = 4;
    else l = 5;
    int e = idx - p.ebase[l];
    const int* epp = p.e[l];
    int row = epp[e];
    int col = epp[p.E[l] + e];
    int g = p.nbase[l] + row;
    int slot = atomicAdd(&cnt[g], 1);
    if (slot < MAXD) ell[g * MAXD + slot].x = col;
  }
}

__global__ void k_wfill(EdgeParams p, const int* __restrict__ cnt, int2* __restrict__ ell, int NT) {
  int total = NT * MAXD;
  for (int idx = blockIdx.x * blockDim.x + threadIdx.x; idx < total; idx += gridDim.x * blockDim.x) {
    int g = idx >> 5;
    int t = idx & (MAXD - 1);
    int dg = cnt[g];
    int d = dg < MAXD ? dg : MAXD;
    if (t < d) {
      int l;
      if (g < p.nbase[1]) l = 0;
      else if (g < p.nbase[2]) l = 1;
      else if (g < p.nbase[3]) l = 2;
      else if (g < p.nbase[4]) l = 3;
      else if (g < p.nbase[5]) l = 4;
      else l = 5;
      int c = ell[idx].x;
      int dc = cnt[p.nbase[l] + c];
      float w = (dc > 0) ? -(rsqrtf((float)dg) * rsqrtf((float)dc)) : 0.0f;
      ell[idx].y = __float_as_int(w);
    }
  }
}

__global__ void k_cvt(const float* __restrict__ in, bf16* __restrict__ out, int N) {
  for (int i = blockIdx.x * blockDim.x + threadIdx.x; i < N; i += gridDim.x * blockDim.x)
    out[i] = __float2bfloat16(in[i]);
}

__global__ void k_xmat(VSrc src, bf16* __restrict__ Xh, int n, int Ctot) {
  int C2 = Ctot >> 1;
  int total = n * C2;
  for (int idx = blockIdx.x * blockDim.x + threadIdx.x; idx < total; idx += gridDim.x * blockDim.x) {
    int i = idx / C2;
    int c2 = idx - i * C2;
    float2 v = vloadh2(src, i, c2);
    *(unsigned*)(Xh + (long)i * Ctot + 2 * c2) = pk2(v.x, v.y);
  }
}

// ---------------- gather kernels ----------------
// t1 = A~ X from flat bf16 X; 4 channels/thread. Writes fp32 + bf16.
__global__ void k_prop_flat(const bf16* __restrict__ Xh, float* __restrict__ T, bf16* __restrict__ Th,
                            const int* __restrict__ cnt, const int2* __restrict__ ell,
                            int nbase, int n, int C) {
  int C4 = C >> 2;
  int total = n * C4;
  for (int idx = blockIdx.x * blockDim.x + threadIdx.x; idx < total; idx += gridDim.x * blockDim.x) {
    int i = idx / C4;
    int c = (idx - i * C4) << 2;
    int g = nbase + i;
    int d = cnt[g]; if (d > MAXD) d = MAXD;
    const int2* cols = ell + (long)g * MAXD;
    float a0 = 0.f, a1 = 0.f, a2 = 0.f, a3 = 0.f;
    for (int t = 0; t < d; t += 8) {
      int ci[8]; float wj[8];
#pragma unroll
      for (int j = 0; j < 8; ++j) {
        int tt = t + j;
        int2 e = cols[(tt < d) ? tt : 0];
        ci[j] = e.x;
        wj[j] = (tt < d) ? __int_as_float(e.y) : 0.f;
      }
#pragma unroll
      for (int j = 0; j < 8; ++j) {
        uint2 raw = *(const uint2*)(Xh + (long)ci[j] * C + c);
        float2 v01 = unpk(raw.x);
        float2 v23 = unpk(raw.y);
        a0 += wj[j] * v01.x;
        a1 += wj[j] * v01.y;
        a2 += wj[j] * v23.x;
        a3 += wj[j] * v23.y;
      }
    }
    long o = (long)i * C + c;
    *(float4*)(T + o) = make_float4(a0, a1, a2, a3);
    uint2 pk; pk.x = pk2(a0, a1); pk.y = pk2(a2, a3);
    *(uint2*)(Th + o) = pk;
  }
}

// t1 = A~ X from virtual source (mid layers); pair of channels/thread.
__global__ void k_prop_v(VSrc src, float* __restrict__ T, bf16* __restrict__ Th,
                         const int* __restrict__ cnt, const int2* __restrict__ ell,
                         int nbase, int n, int C) {
  int C2 = C >> 1;
  int total = n * C2;
  for (int idx = blockIdx.x * blockDim.x + threadIdx.x; idx < total; idx += gridDim.x * blockDim.x) {
    int i = idx / C2;
    int c2 = idx - i * C2;
    int g = nbase + i;
    int d = cnt[g]; if (d > MAXD) d = MAXD;
    const int2* cols = ell + (long)g * MAXD;
    float ax = 0.f, ay = 0.f;
    for (int t = 0; t < d; t += 8) {
      int ci[8]; float wj[8];
#pragma unroll
      for (int j = 0; j < 8; ++j) {
        int tt = t + j;
        int2 e = cols[(tt < d) ? tt : 0];
        ci[j] = e.x;
        wj[j] = (tt < d) ? __int_as_float(e.y) : 0.f;
      }
#pragma unroll
      for (int j = 0; j < 8; ++j) {
        float2 v = vloadh2(src, ci[j], c2);
        ax += wj[j] * v.x;
        ay += wj[j] * v.y;
      }
    }
    long o = (long)i * C + 2 * c2;
    ((float2*)T)[o >> 1] = make_float2(ax, ay);
    *(unsigned*)(Th + o) = pk2(ax, ay);
  }
}

// t2 = 2 * A~ t1 - x ; gathers T1h (flat bf16), x via virtual fp32. Writes fp32 only.
__global__ void k_prop2(VSrc src, const bf16* __restrict__ T1h, float* __restrict__ T2,
                        const int* __restrict__ cnt, const int2* __restrict__ ell,
                        int nbase, int n, int C) {
  int C4 = C >> 2;
  int total = n * C4;
  for (int idx = blockIdx.x * blockDim.x + threadIdx.x; idx < total; idx += gridDim.x * blockDim.x) {
    int i = idx / C4;
    int c = (idx - i * C4) << 2;
    int g = nbase + i;
    int d = cnt[g]; if (d > MAXD) d = MAXD;
    const int2* cols = ell + (long)g * MAXD;
    float a0 = 0.f, a1 = 0.f, a2 = 0.f, a3 = 0.f;
    for (int t = 0; t < d; t += 8) {
      int ci[8]; float wj[8];
#pragma unroll
      for (int j = 0; j < 8; ++j) {
        int tt = t + j;
        int2 e = cols[(tt < d) ? tt : 0];
        ci[j] = e.x;
        wj[j] = (tt < d) ? __int_as_float(e.y) : 0.f;
      }
#pragma unroll
      for (int j = 0; j < 8; ++j) {
        uint2 raw = *(const uint2*)(T1h + (long)ci[j] * C + c);
        float2 v01 = unpk(raw.x);
        float2 v23 = unpk(raw.y);
        a0 += wj[j] * v01.x;
        a1 += wj[j] * v01.y;
        a2 += wj[j] * v23.x;
        a3 += wj[j] * v23.y;
      }
    }
    float x0 = vloadf(src, i, c);
    float x1 = vloadf(src, i, c + 1);
    float x2 = vloadf(src, i, c + 2);
    float x3 = vloadf(src, i, c + 3);
    long o = (long)i * C + c;
    *(float4*)(T2 + o) = make_float4(2.f * a0 - x0, 2.f * a1 - x1, 2.f * a2 - x2, 2.f * a3 - x3);
  }
}

// ---------------- combine: [X|t1|t2] @ W + b (+relu / +softmax) ----------------
// GATHER=1: t2 computed in-kernel by gathering T1h. GATHER=0: t2 read as stream from T2s.
template <int ROWS, int CW, int SMAX, int GATHER>
__global__ __launch_bounds__(256) void k_combine(
    VSrc src, const float* __restrict__ T1, const bf16* __restrict__ T1h,
    const float* __restrict__ T2s,
    const float* __restrict__ W, const float* __restrict__ B,
    const int* __restrict__ cnt, const int2* __restrict__ ell,
    int nbase, int n, int Cin, int Cout, int doRelu,
    float* __restrict__ OUT, bf16* __restrict__ OUTh) {
  constexpr int RW = 4 / CW;
  constexpr int RPW = ROWS / RW;

  __shared__ __align__(16) float sx[4][RPW][64];
  __shared__ __align__(16) float st1[4][RPW][64];
  __shared__ __align__(16) float st2[4][RPW][64];

  int tid = threadIdx.x;
  int w = tid >> 6;
  int lane = tid & 63;
  int rg = w / CW;
  int cw = w % CW;

  int colTiles = (Cout + 63) >> 6;
  int ct = blockIdx.x % colTiles;
  int rt = blockIdx.x / colTiles;
  int r0 = rt * ROWS + rg * RPW;
  int o = ct * 64 + lane;
  int oc = (o < Cout) ? o : (Cout - 1);
  int nch = (Cin + 63) >> 6;

  float acc[RPW];
#pragma unroll
  for (int r = 0; r < RPW; ++r) acc[r] = 0.f;

  for (int cg = 0; cg < nch; cg += CW) {
    int c = cg + cw;
    bool act = c < nch;
    int k0 = c * 64;
    int kw = act ? ((Cin - k0 < 64) ? (Cin - k0) : 64) : 0;
    int k = k0 + lane;
    bool kv = act && (lane < kw);

#pragma unroll
    for (int rr = 0; rr < RPW; ++rr) {
      int i = r0 + rr;
      bool iv = i < n;
      float xv = 0.f, tv = 0.f, t2v = 0.f;
      if (kv && iv) {
        xv = vloadf(src, i, k);
        tv = T1[(long)i * Cin + k];
        if constexpr (GATHER) {
          int g = nbase + i;
          int d = cnt[g]; if (d > MAXD) d = MAXD;
          const int2* cols = ell + (long)g * MAXD;
          float a2 = 0.f;
          for (int t = 0; t < d; t += 8) {
            int ci[8]; float wj[8];
#pragma unroll
            for (int j = 0; j < 8; ++j) {
              int tt = t + j;
              int2 e = cols[(tt < d) ? tt : 0];
              ci[j] = e.x;
              wj[j] = (tt < d) ? __int_as_float(e.y) : 0.f;
            }
#pragma unroll
            for (int j = 0; j < 8; ++j)
              a2 += wj[j] * bf2f(T1h[(long)ci[j] * Cin + k]);
          }
          t2v = 2.f * a2 - xv;
        } else {
          t2v = T2s[(long)i * Cin + k];
        }
      }
      sx[w][rr][lane] = xv;
      st1[w][rr][lane] = tv;
      st2[w][rr][lane] = t2v;
    }
    __syncthreads();

    int kw4 = kw >> 2;
    long ts = (long)Cin * Cout;
    for (int q = 0; q < kw4; ++q) {
      float w0[4], w1[4], w2[4];
#pragma unroll
      for (int j = 0; j < 4; ++j) {
        long off = (long)(k0 + q * 4 + j) * Cout + oc;
        w0[j] = W[off];
        w1[j] = W[ts + off];
        w2[j] = W[2 * ts + off];
      }
#pragma unroll
      for (int rr = 0; rr < RPW; ++rr) {
        float4 xs = ((const float4*)sx[w][rr])[q];
        float4 t1s = ((const float4*)st1[w][rr])[q];
        float4 t2s = ((const float4*)st2[w][rr])[q];
        acc[rr] += w0[0] * xs.x + w0[1] * xs.y + w0[2] * xs.z + w0[3] * xs.w;
        acc[rr] += w1[0] * t1s.x + w1[1] * t1s.y + w1[2] * t1s.z + w1[3] * t1s.w;
        acc[rr] += w2[0] * t2s.x + w2[1] * t2s.y + w2[2] * t2s.z + w2[3] * t2s.w;
      }
    }
    __syncthreads();
  }

  if constexpr (SMAX) {
    float bb = (o < Cout) ? B[o] : 0.f;
#pragma unroll
    for (int rr = 0; rr < RPW; ++rr) {
      int i = r0 + rr;
      if (i < n) {
        float v = (o < Cout) ? (acc[rr] + bb) : -1e30f;
        float m = v;
        for (int s = 32; s > 0; s >>= 1) m = fmaxf(m, __shfl_xor(m, s));
        float e = (o < Cout) ? __expf(v - m) : 0.f;
        float sum = e;
        for (int s = 32; s > 0; s >>= 1) sum += __shfl_xor(sum, s);
        if (o < Cout) OUT[(long)i * Cout + o] = e / sum;
      }
    }
  } else if constexpr (CW == 1) {
    if (o < Cout) {
      float bb = B[oc];
#pragma unroll
      for (int rr = 0; rr < RPW; ++rr) {
        int i = r0 + rr;
        if (i < n) {
          float v = acc[rr] + bb;
          if (doRelu) v = fmaxf(v, 0.f);
          long off = (long)i * Cout + o;
          OUT[off] = v;
          OUTh[off] = __float2bfloat16(v);
        }
      }
    }
  } else {
#pragma unroll
    for (int rr = 0; rr < RPW; ++rr) sx[w][rr][lane] = acc[rr];
    __syncthreads();
    if (cw == 0 && o < Cout) {
      float bb = B[oc];
#pragma unroll
      for (int rr = 0; rr < RPW; ++rr) {
        int i = r0 + rr;
        if (i < n) {
          float v = bb;
#pragma unroll
          for (int j = 0; j < CW; ++j) v += sx[rg * CW + j][rr][lane];
          if (doRelu) v = fmaxf(v, 0.f);
          long off = (long)i * Cout + o;
          OUT[off] = v;
          OUTh[off] = __float2bfloat16(v);
        }
      }
    }
  }
}

// ---------------- launcher ----------------
extern "C" void kernel_launch(void* const* d_in, const int* in_sizes, int n_in,
                              void* d_out, int out_size, void* d_ws, size_t ws_size,
                              hipStream_t stream) {
  static const int NV[6] = {42, 162, 642, 2562, 10242, 40962};
  static const int NE[6] = {240, 960, 3840, 15360, 61440, 245760};
  const int NT = 54612;
  const int ET = 327600;

  EdgeParams ep;
  {
    int nb = 0, eb = 0;
    for (int l = 0; l < 6; ++l) {
      ep.e[l] = (const int*)d_in[1 + l];
      ep.E[l] = NE[l];
      ep.ebase[l] = eb;
      ep.nbase[l] = nb;
      eb += NE[l];
      nb += NV[l];
    }
  }
  const float* x0f = (const float*)d_in[0];
  const int* up[5];
  for (int i = 0; i < 5; ++i) up[i] = (const int*)d_in[7 + i];  // up2..up6
  const float *W[11], *Bb[11];
  for (int i = 0; i < 11; ++i) {
    W[i] = (const float*)d_in[12 + 2 * i];
    Bb[i] = (const float*)d_in[13 + 2 * i];
  }

  // ---- workspace carve (16B-aligned) ----
  char* p = (char*)d_ws;
  auto alloc_b = [&](size_t bytes) { void* r = (void*)p; p += (bytes + 15) & ~size_t(15); return r; };
  auto alloc_i = [&](size_t ne) { return (int*)alloc_b(ne * 4); };
  auto alloc_f = [&](size_t ne) { return (float*)alloc_b(ne * 4); };
  auto alloc_h = [&](size_t ne) { return (bf16*)alloc_b(ne * 2); };
  int* cnt = alloc_i(NT);
  int2* ell = (int2*)alloc_b((size_t)NT * MAXD * 8);
  float* t1f = alloc_f((size_t)40962 * 36);
  bf16* t1h = alloc_h((size_t)40962 * 36);
  float* t2f = alloc_f((size_t)40962 * 36);
  bf16* x0h = alloc_h((size_t)40962 * 4);
  bf16* xh = alloc_h((size_t)40962 * 36);  // big-layer materialized upcat source (bf16)
  float *af[10]; bf16 *ah[10];
  const int an[10] = {40962, 10242, 2562, 642, 162, 42, 162, 642, 2562, 10242};
  const int ac[10] = {32, 64, 128, 256, 512, 512, 256, 128, 64, 32};
  for (int i = 0; i < 10; ++i) {
    af[i] = alloc_f((size_t)an[i] * ac[i]);
    ah[i] = alloc_h((size_t)an[i] * ac[i]);
  }

  hipMemsetAsync(cnt, 0, (size_t)NT * 4, stream);
  k_fill<<<(ET + 255) / 256, 256, 0, stream>>>(ep, cnt, ell, ET);
  k_wfill<<<(NT * MAXD + 255) / 256, 256, 0, stream>>>(ep, cnt, ell, NT);
  k_cvt<<<(40962 * 4 + 255) / 256, 256, 0, stream>>>(x0f, x0h, 40962 * 4);

  auto plain = [](const float* hf, const bf16* hh, int Ch) {
    VSrc s{hf, hh, nullptr, nullptr, nullptr, 0, Ch, 0}; return s;
  };
  auto upsrc = [](const float* hf, const bf16* hh, const float* skf, const bf16* skh,
                  const int* u, int nprev, int Ch, int Cs) {
    VSrc s{hf, hh, skf, skh, u, nprev, Ch, Cs}; return s;
  };

  // big layer: flat prop + prop2 + streaming combine
  auto big = [&](const bf16* Xh, VSrc s, float* OUT, bf16* OUTh, int lvl, int n, int Cin,
                 int Cout, const float* Wp, const float* Bp, int smax) {
    int nb = ep.nbase[lvl];
    int t4 = n * (Cin >> 2);
    k_prop_flat<<<(t4 + 255) / 256, 256, 0, stream>>>(Xh, t1f, t1h, cnt, ell, nb, n, Cin);
    k_prop2<<<(t4 + 255) / 256, 256, 0, stream>>>(s, t1h, t2f, cnt, ell, nb, n, Cin);
    int grid = ((Cout + 63) / 64) * ((n + 7) / 8);
    if (smax)
      k_combine<8, 1, 1, 0><<<grid, 256, 0, stream>>>(s, t1f, t1h, t2f, Wp, Bp, cnt, ell, nb, n, Cin, Cout, 0, OUT, OUTh);
    else
      k_combine<8, 1, 0, 0><<<grid, 256, 0, stream>>>(s, t1f, t1h, t2f, Wp, Bp, cnt, ell, nb, n, Cin, Cout, 1, OUT, OUTh);
  };

  // mid layer: virtual prop + gather-combine
  auto mid = [&](VSrc s, float* OUT, bf16* OUTh, int lvl, int n, int Cin, int Cout,
                 const float* Wp, const float* Bp, int rows, int cwv) {
    int nb = ep.nbase[lvl];
    int t2 = n * (Cin >> 1);
    k_prop_v<<<(t2 + 255) / 256, 256, 0, stream>>>(s, t1f, t1h, cnt, ell, nb, n, Cin);
    int grid = ((Cout + 63) / 64) * ((n + rows - 1) / rows);
    if (rows == 8 && cwv == 1)
      k_combine<8, 1, 0, 1><<<grid, 256, 0, stream>>>(s, t1f, t1h, nullptr, Wp, Bp, cnt, ell, nb, n, Cin, Cout, 1, OUT, OUTh);
    else if (rows == 8 && cwv == 2)
      k_combine<8, 2, 0, 1><<<grid, 256, 0, stream>>>(s, t1f, t1h, nullptr, Wp, Bp, cnt, ell, nb, n, Cin, Cout, 1, OUT, OUTh);
    else
      k_combine<4, 4, 0, 1><<<grid, 256, 0, stream>>>(s, t1f, t1h, nullptr, Wp, Bp, cnt, ell, nb, n, Cin, Cout, 1, OUT, OUTh);
  };

  // ---- L1: n=40962, 4->32 ----
  big(x0h, plain(x0f, x0h, 4), af[0], ah[0], 5, 40962, 4, 32, W[0], Bb[0], 0);
  // ---- L2: n=10242, 32->64 ----
  big(ah[0], plain(af[0], ah[0], 32), af[1], ah[1], 4, 10242, 32, 64, W[1], Bb[1], 0);
  // ---- mid encoder ----
  mid(plain(af[1], ah[1], 64), af[2], ah[2], 3, 2562, 64, 128, W[2], Bb[2], 8, 1);
  mid(plain(af[2], ah[2], 128), af[3], ah[3], 2, 642, 128, 256, W[3], Bb[3], 8, 2);
  mid(plain(af[3], ah[3], 256), af[4], ah[4], 1, 162, 256, 512, W[4], Bb[4], 4, 4);
  mid(plain(af[4], ah[4], 512), af[5], ah[5], 0, 42, 512, 512, W[5], Bb[5], 4, 4);
  // ---- mid decoder ----
  mid(upsrc(af[5], ah[5], af[3], ah[3], up[0], 42, 512, 256), af[6], ah[6], 1, 162, 768, 256, W[6], Bb[6], 4, 4);
  mid(upsrc(af[6], ah[6], af[2], ah[2], up[1], 162, 256, 128), af[7], ah[7], 2, 642, 384, 128, W[7], Bb[7], 4, 4);
  mid(upsrc(af[7], ah[7], af[1], ah[1], up[2], 642, 128, 64), af[8], ah[8], 3, 2562, 192, 64, W[8], Bb[8], 8, 2);
  // ---- L10: n=10242, [64|32]->32 ----
  {
    VSrc s = upsrc(af[8], ah[8], af[0], ah[0], up[3], 2562, 64, 32);
    k_xmat<<<(10242 * 48 + 255) / 256, 256, 0, stream>>>(s, xh, 10242, 96);
    big(xh, s, af[9], ah[9], 4, 10242, 96, 32, W[9], Bb[9], 0);
  }
  // ---- L11: n=40962, [32|4]->37 + softmax ----
  {
    VSrc s = upsrc(af[9], ah[9], x0f, x0h, up[4], 10242, 32, 4);
    k_xmat<<<(40962 * 18 + 255) / 256, 256, 0, stream>>>(s, xh, 40962, 36);
    big(xh, s, (float*)d_out, nullptr, 5, 40962, 36, 37, W[10], Bb[10], 1);
  }
}

// Round 8
// 535.752 us; speedup vs baseline: 4.9629x; 1.0137x over previous
//
#include <hip/hip_runtime.h>
#include <hip/hip_bf16.h>

#define MAXD 32
typedef __hip_bfloat16 bf16;

__device__ __forceinline__ float bf2f(bf16 v) { return __bfloat162float(v); }
__device__ __forceinline__ float2 ldbf2(const bf16* p) {
  unsigned u = *(const unsigned*)p;
  return make_float2(__uint_as_float(u << 16), __uint_as_float(u & 0xffff0000u));
}
__device__ __forceinline__ float2 unpk(unsigned u) {
  return make_float2(__uint_as_float(u << 16), __uint_as_float(u & 0xffff0000u));
}
__device__ __forceinline__ unsigned pk2(float x, float y) {
  bf16 bx = __float2bfloat16(x), by = __float2bfloat16(y);
  unsigned short ux, uy;
  __builtin_memcpy(&ux, &bx, 2);
  __builtin_memcpy(&uy, &by, 2);
  return (unsigned)ux | ((unsigned)uy << 16);
}

struct EdgeParams {
  const int* e[6];
  int E[6];
  int ebase[6];
  int nbase[6];
};

struct VSrc {
  const float* hf; const bf16* hh;
  const float* skf; const bf16* skh;
  const int* up;
  int nprev, Ch, Cs;
};

__device__ __forceinline__ float vloadf(const VSrc& s, int i, int c) {
  if (s.up) {
    if (c >= s.Ch) return s.skf[(long)i * s.Cs + (c - s.Ch)];
    if (i >= s.nprev) {
      int j = i - s.nprev;
      int u0 = s.up[2 * j], u1 = s.up[2 * j + 1];
      return 0.5f * (s.hf[(long)u0 * s.Ch + c] + s.hf[(long)u1 * s.Ch + c]);
    }
    return s.hf[(long)i * s.Ch + c];
  }
  return s.hf[(long)i * s.Ch + c];
}

__device__ __forceinline__ float2 vloadh2(const VSrc& s, int i, int c2) {
  int c = 2 * c2;
  if (s.up) {
    if (c >= s.Ch) return ldbf2(s.skh + (long)i * s.Cs + (c - s.Ch));
    if (i >= s.nprev) {
      int j = i - s.nprev;
      int u0 = s.up[2 * j], u1 = s.up[2 * j + 1];
      float2 a = ldbf2(s.hh + (long)u0 * s.Ch + c);
      float2 b = ldbf2(s.hh + (long)u1 * s.Ch + c);
      return make_float2(0.5f * (a.x + b.x), 0.5f * (a.y + b.y));
    }
    return ldbf2(s.hh + (long)i * s.Ch + c);
  }
  return ldbf2(s.hh + (long)i * s.Ch + c);
}

// ---------------- setup kernels ----------------
__global__ void k_fill(EdgeParams p, int* __restrict__ cnt, int2* __restrict__ ell, int ET) {
  for (int idx = blockIdx.x * blockDim.x + threadIdx.x; idx < ET; idx += gridDim.x * blockDim.x) {
    int l;
    if (idx < p.ebase[1]) l = 0;
    else if (idx < p.ebase[2]) l = 1;
    else if (idx < p.ebase[3]) l = 2;
    else if (idx < p.ebase[4]) l = 3;
    else if (idx < p.ebase[5]) l = 4;
    else l = 5;
    int e = idx - p.ebase[l];
    const int* epp = p.e[l];
    int row = epp[e];
    int col = epp[p.E[l] + e];
    int g = p.nbase[l] + row;
    int slot = atomicAdd(&cnt[g], 1);
    if (slot < MAXD) ell[g * MAXD + slot].x = col;
  }
}

__global__ void k_wfill(EdgeParams p, const int* __restrict__ cnt, int2* __restrict__ ell, int NT) {
  int total = NT * MAXD;
  for (int idx = blockIdx.x * blockDim.x + threadIdx.x; idx < total; idx += gridDim.x * blockDim.x) {
    int g = idx >> 5;
    int t = idx & (MAXD - 1);
    int dg = cnt[g];
    int d = dg < MAXD ? dg : MAXD;
    if (t < d) {
      int l;
      if (g < p.nbase[1]) l = 0;
      else if (g < p.nbase[2]) l = 1;
      else if (g < p.nbase[3]) l = 2;
      else if (g < p.nbase[4]) l = 3;
      else if (g < p.nbase[5]) l = 4;
      else l = 5;
      int c = ell[idx].x;
      int dc = cnt[p.nbase[l] + c];
      float w = (dc > 0) ? -(rsqrtf((float)dg) * rsqrtf((float)dc)) : 0.0f;
      ell[idx].y = __float_as_int(w);
    }
  }
}

__global__ void k_cvt(const float* __restrict__ in, bf16* __restrict__ out, int N) {
  for (int i = blockIdx.x * blockDim.x + threadIdx.x; i < N; i += gridDim.x * blockDim.x)
    out[i] = __float2bfloat16(in[i]);
}

// Repack W[3][Cin][Cout] -> Wp[3][Cin/4][Cout][4] (k-grouped float4), all 11 layers.
struct WPack {
  const float* src[11];
  float* dst[11];
  int cin[11], cout[11], tot[11];
};
__global__ void k_wpack(WPack P, int TOT) {
  for (int idx = blockIdx.x * blockDim.x + threadIdx.x; idx < TOT; idx += gridDim.x * blockDim.x) {
    int l = 0, off = idx;
    while (off >= P.tot[l]) { off -= P.tot[l]; ++l; }
    int cout = P.cout[l];
    int cinco = P.cin[l] * cout;
    int t = off / cinco;
    int rem = off - t * cinco;
    int k = rem / cout;
    int o = rem - k * cout;
    P.dst[l][((t * (P.cin[l] >> 2) + (k >> 2)) * cout + o) * 4 + (k & 3)] = P.src[l][off];
  }
}

__global__ void k_xmat(VSrc src, bf16* __restrict__ Xh, int n, int Ctot) {
  int C2 = Ctot >> 1;
  int total = n * C2;
  for (int idx = blockIdx.x * blockDim.x + threadIdx.x; idx < total; idx += gridDim.x * blockDim.x) {
    int i = idx / C2;
    int c2 = idx - i * C2;
    float2 v = vloadh2(src, i, c2);
    *(unsigned*)(Xh + (long)i * Ctot + 2 * c2) = pk2(v.x, v.y);
  }
}

// ---------------- gather kernels ----------------
__global__ void k_prop_flat(const bf16* __restrict__ Xh, float* __restrict__ T, bf16* __restrict__ Th,
                            const int* __restrict__ cnt, const int2* __restrict__ ell,
                            int nbase, int n, int C) {
  int C4 = C >> 2;
  int total = n * C4;
  for (int idx = blockIdx.x * blockDim.x + threadIdx.x; idx < total; idx += gridDim.x * blockDim.x) {
    int i = idx / C4;
    int c = (idx - i * C4) << 2;
    int g = nbase + i;
    int d = cnt[g]; if (d > MAXD) d = MAXD;
    const int2* cols = ell + (long)g * MAXD;
    float a0 = 0.f, a1 = 0.f, a2 = 0.f, a3 = 0.f;
    for (int t = 0; t < d; t += 8) {
      int ci[8]; float wj[8];
#pragma unroll
      for (int j = 0; j < 8; ++j) {
        int tt = t + j;
        int2 e = cols[(tt < d) ? tt : 0];
        ci[j] = e.x;
        wj[j] = (tt < d) ? __int_as_float(e.y) : 0.f;
      }
#pragma unroll
      for (int j = 0; j < 8; ++j) {
        uint2 raw = *(const uint2*)(Xh + (long)ci[j] * C + c);
        float2 v01 = unpk(raw.x);
        float2 v23 = unpk(raw.y);
        a0 += wj[j] * v01.x;
        a1 += wj[j] * v01.y;
        a2 += wj[j] * v23.x;
        a3 += wj[j] * v23.y;
      }
    }
    long o = (long)i * C + c;
    *(float4*)(T + o) = make_float4(a0, a1, a2, a3);
    uint2 pk; pk.x = pk2(a0, a1); pk.y = pk2(a2, a3);
    *(uint2*)(Th + o) = pk;
  }
}

__global__ void k_prop_v(VSrc src, float* __restrict__ T, bf16* __restrict__ Th,
                         const int* __restrict__ cnt, const int2* __restrict__ ell,
                         int nbase, int n, int C) {
  int C2 = C >> 1;
  int total = n * C2;
  for (int idx = blockIdx.x * blockDim.x + threadIdx.x; idx < total; idx += gridDim.x * blockDim.x) {
    int i = idx / C2;
    int c2 = idx - i * C2;
    int g = nbase + i;
    int d = cnt[g]; if (d > MAXD) d = MAXD;
    const int2* cols = ell + (long)g * MAXD;
    float ax = 0.f, ay = 0.f;
    for (int t = 0; t < d; t += 8) {
      int ci[8]; float wj[8];
#pragma unroll
      for (int j = 0; j < 8; ++j) {
        int tt = t + j;
        int2 e = cols[(tt < d) ? tt : 0];
        ci[j] = e.x;
        wj[j] = (tt < d) ? __int_as_float(e.y) : 0.f;
      }
#pragma unroll
      for (int j = 0; j < 8; ++j) {
        float2 v = vloadh2(src, ci[j], c2);
        ax += wj[j] * v.x;
        ay += wj[j] * v.y;
      }
    }
    long o = (long)i * C + 2 * c2;
    ((float2*)T)[o >> 1] = make_float2(ax, ay);
    *(unsigned*)(Th + o) = pk2(ax, ay);
  }
}

__global__ void k_prop2(VSrc src, const bf16* __restrict__ T1h, float* __restrict__ T2,
                        const int* __restrict__ cnt, const int2* __restrict__ ell,
                        int nbase, int n, int C) {
  int C4 = C >> 2;
  int total = n * C4;
  for (int idx = blockIdx.x * blockDim.x + threadIdx.x; idx < total; idx += gridDim.x * blockDim.x) {
    int i = idx / C4;
    int c = (idx - i * C4) << 2;
    int g = nbase + i;
    int d = cnt[g]; if (d > MAXD) d = MAXD;
    const int2* cols = ell + (long)g * MAXD;
    float a0 = 0.f, a1 = 0.f, a2 = 0.f, a3 = 0.f;
    for (int t = 0; t < d; t += 8) {
      int ci[8]; float wj[8];
#pragma unroll
      for (int j = 0; j < 8; ++j) {
        int tt = t + j;
        int2 e = cols[(tt < d) ? tt : 0];
        ci[j] = e.x;
        wj[j] = (tt < d) ? __int_as_float(e.y) : 0.f;
      }
#pragma unroll
      for (int j = 0; j < 8; ++j) {
        uint2 raw = *(const uint2*)(T1h + (long)ci[j] * C + c);
        float2 v01 = unpk(raw.x);
        float2 v23 = unpk(raw.y);
        a0 += wj[j] * v01.x;
        a1 += wj[j] * v01.y;
        a2 += wj[j] * v23.x;
        a3 += wj[j] * v23.y;
      }
    }
    float x0 = vloadf(src, i, c);
    float x1 = vloadf(src, i, c + 1);
    float x2 = vloadf(src, i, c + 2);
    float x3 = vloadf(src, i, c + 3);
    long o = (long)i * C + c;
    *(float4*)(T2 + o) = make_float4(2.f * a0 - x0, 2.f * a1 - x1, 2.f * a2 - x2, 2.f * a3 - x3);
  }
}

// ---------------- combine: [X|t1|t2] @ Wp + b (+relu / +softmax) ----------------
// Wp is k-grouped float4: [3][Cin/4][Cout][4].
// GATHER=1: t2 gathered from T1h in-kernel; GATHER=0: t2 streamed from T2s.
template <int ROWS, int CW, int SMAX, int GATHER>
__global__ __launch_bounds__(256) void k_combine(
    VSrc src, const float* __restrict__ T1, const bf16* __restrict__ T1h,
    const float* __restrict__ T2s,
    const float4* __restrict__ Wp, const float* __restrict__ B,
    const int* __restrict__ cnt, const int2* __restrict__ ell,
    int nbase, int n, int Cin, int Cout, int doRelu,
    float* __restrict__ OUT, bf16* __restrict__ OUTh) {
  constexpr int RW = 4 / CW;
  constexpr int RPW = (ROWS * CW) / 4;
  static_assert(RPW * RW == ROWS, "bad ROWS/CW combo");

  __shared__ __align__(16) float sx[4][RPW][64];
  __shared__ __align__(16) float st1[4][RPW][64];
  __shared__ __align__(16) float st2[4][RPW][64];

  int tid = threadIdx.x;
  int w = tid >> 6;
  int lane = tid & 63;
  int rg = w / CW;
  int cw = w % CW;

  int colTiles = (Cout + 63) >> 6;
  int ct = blockIdx.x % colTiles;
  int rt = blockIdx.x / colTiles;
  int r0 = rt * ROWS + rg * RPW;
  int o = ct * 64 + lane;
  int oc = (o < Cout) ? o : (Cout - 1);
  int nch = (Cin + 63) >> 6;
  int KQ = Cin >> 2;

  float acc[RPW];
#pragma unroll
  for (int r = 0; r < RPW; ++r) acc[r] = 0.f;

  for (int cg = 0; cg < nch; cg += CW) {
    int c = cg + cw;
    bool act = c < nch;
    int k0 = c * 64;
    int kw = act ? ((Cin - k0 < 64) ? (Cin - k0) : 64) : 0;
    int k = k0 + lane;
    bool kv = act && (lane < kw);

#pragma unroll
    for (int rr = 0; rr < RPW; ++rr) {
      int i = r0 + rr;
      bool iv = i < n;
      float xv = 0.f, tv = 0.f, t2v = 0.f;
      if (kv && iv) {
        xv = vloadf(src, i, k);
        tv = T1[(long)i * Cin + k];
        if constexpr (GATHER) {
          int g = nbase + i;
          int d = cnt[g]; if (d > MAXD) d = MAXD;
          const int2* cols = ell + (long)g * MAXD;
          float a2 = 0.f;
          for (int t = 0; t < d; t += 8) {
            int ci[8]; float wj[8];
#pragma unroll
            for (int j = 0; j < 8; ++j) {
              int tt = t + j;
              int2 e = cols[(tt < d) ? tt : 0];
              ci[j] = e.x;
              wj[j] = (tt < d) ? __int_as_float(e.y) : 0.f;
            }
#pragma unroll
            for (int j = 0; j < 8; ++j)
              a2 += wj[j] * bf2f(T1h[(long)ci[j] * Cin + k]);
          }
          t2v = 2.f * a2 - xv;
        } else {
          t2v = T2s[(long)i * Cin + k];
        }
      }
      sx[w][rr][lane] = xv;
      st1[w][rr][lane] = tv;
      st2[w][rr][lane] = t2v;
    }
    __syncthreads();

    int kw4 = kw >> 2;
    for (int q = 0; q < kw4; ++q) {
      int kq = (k0 >> 2) + q;
      float4 w0 = Wp[(0 * KQ + kq) * Cout + oc];
      float4 w1 = Wp[(1 * KQ + kq) * Cout + oc];
      float4 w2 = Wp[(2 * KQ + kq) * Cout + oc];
#pragma unroll
      for (int rr = 0; rr < RPW; ++rr) {
        float4 xs = ((const float4*)sx[w][rr])[q];
        float4 t1s = ((const float4*)st1[w][rr])[q];
        float4 t2s = ((const float4*)st2[w][rr])[q];
        acc[rr] += w0.x * xs.x + w0.y * xs.y + w0.z * xs.z + w0.w * xs.w;
        acc[rr] += w1.x * t1s.x + w1.y * t1s.y + w1.z * t1s.z + w1.w * t1s.w;
        acc[rr] += w2.x * t2s.x + w2.y * t2s.y + w2.z * t2s.z + w2.w * t2s.w;
      }
    }
    __syncthreads();
  }

  if constexpr (SMAX) {
    float bb = (o < Cout) ? B[o] : 0.f;
#pragma unroll
    for (int rr = 0; rr < RPW; ++rr) {
      int i = r0 + rr;
      if (i < n) {
        float v = (o < Cout) ? (acc[rr] + bb) : -1e30f;
        float m = v;
        for (int s = 32; s > 0; s >>= 1) m = fmaxf(m, __shfl_xor(m, s));
        float e = (o < Cout) ? __expf(v - m) : 0.f;
        float sum = e;
        for (int s = 32; s > 0; s >>= 1) sum += __shfl_xor(sum, s);
        if (o < Cout) OUT[(long)i * Cout + o] = e / sum;
      }
    }
  } else if constexpr (CW == 1) {
    if (o < Cout) {
      float bb = B[oc];
#pragma unroll
      for (int rr = 0; rr < RPW; ++rr) {
        int i = r0 + rr;
        if (i < n) {
          float v = acc[rr] + bb;
          if (doRelu) v = fmaxf(v, 0.f);
          long off = (long)i * Cout + o;
          OUT[off] = v;
          OUTh[off] = __float2bfloat16(v);
        }
      }
    }
  } else {
#pragma unroll
    for (int rr = 0; rr < RPW; ++rr) sx[w][rr][lane] = acc[rr];
    __syncthreads();
    if (cw == 0 && o < Cout) {
      float bb = B[oc];
#pragma unroll
      for (int rr = 0; rr < RPW; ++rr) {
        int i = r0 + rr;
        if (i < n) {
          float v = bb;
#pragma unroll
          for (int j = 0; j < CW; ++j) v += sx[rg * CW + j][rr][lane];
          if (doRelu) v = fmaxf(v, 0.f);
          long off = (long)i * Cout + o;
          OUT[off] = v;
          OUTh[off] = __float2bfloat16(v);
        }
      }
    }
  }
}

// ---------------- launcher ----------------
extern "C" void kernel_launch(void* const* d_in, const int* in_sizes, int n_in,
                              void* d_out, int out_size, void* d_ws, size_t ws_size,
                              hipStream_t stream) {
  static const int NV[6] = {42, 162, 642, 2562, 10242, 40962};
  static const int NE[6] = {240, 960, 3840, 15360, 61440, 245760};
  const int NT = 54612;
  const int ET = 327600;

  EdgeParams ep;
  {
    int nb = 0, eb = 0;
    for (int l = 0; l < 6; ++l) {
      ep.e[l] = (const int*)d_in[1 + l];
      ep.E[l] = NE[l];
      ep.ebase[l] = eb;
      ep.nbase[l] = nb;
      eb += NE[l];
      nb += NV[l];
    }
  }
  const float* x0f = (const float*)d_in[0];
  const int* up[5];
  for (int i = 0; i < 5; ++i) up[i] = (const int*)d_in[7 + i];  // up2..up6
  const float *W[11], *Bb[11];
  for (int i = 0; i < 11; ++i) {
    W[i] = (const float*)d_in[12 + 2 * i];
    Bb[i] = (const float*)d_in[13 + 2 * i];
  }
  static const int LCI[11] = {4, 32, 64, 128, 256, 512, 768, 384, 192, 96, 36};
  static const int LCO[11] = {32, 64, 128, 256, 512, 512, 256, 128, 64, 32, 37};

  // ---- workspace carve (16B-aligned) ----
  char* p = (char*)d_ws;
  auto alloc_b = [&](size_t bytes) { void* r = (void*)p; p += (bytes + 15) & ~size_t(15); return r; };
  auto alloc_i = [&](size_t ne) { return (int*)alloc_b(ne * 4); };
  auto alloc_f = [&](size_t ne) { return (float*)alloc_b(ne * 4); };
  auto alloc_h = [&](size_t ne) { return (bf16*)alloc_b(ne * 2); };
  int* cnt = alloc_i(NT);
  int2* ell = (int2*)alloc_b((size_t)NT * MAXD * 8);
  float* t1f = alloc_f((size_t)40962 * 36);
  bf16* t1h = alloc_h((size_t)40962 * 36);
  float* t2f = alloc_f((size_t)40962 * 36);
  bf16* x0h = alloc_h((size_t)40962 * 4);
  bf16* xh = alloc_h((size_t)40962 * 36);
  float* wp[11];
  for (int i = 0; i < 11; ++i) wp[i] = alloc_f((size_t)3 * LCI[i] * LCO[i]);
  float *af[10]; bf16 *ah[10];
  const int an[10] = {40962, 10242, 2562, 642, 162, 42, 162, 642, 2562, 10242};
  const int ac[10] = {32, 64, 128, 256, 512, 512, 256, 128, 64, 32};
  for (int i = 0; i < 10; ++i) {
    af[i] = alloc_f((size_t)an[i] * ac[i]);
    ah[i] = alloc_h((size_t)an[i] * ac[i]);
  }

  hipMemsetAsync(cnt, 0, (size_t)NT * 4, stream);
  k_fill<<<(ET + 255) / 256, 256, 0, stream>>>(ep, cnt, ell, ET);
  k_wfill<<<(NT * MAXD + 255) / 256, 256, 0, stream>>>(ep, cnt, ell, NT);
  k_cvt<<<(40962 * 4 + 255) / 256, 256, 0, stream>>>(x0f, x0h, 40962 * 4);
  {
    WPack P;
    int TOT = 0;
    for (int i = 0; i < 11; ++i) {
      P.src[i] = W[i];
      P.dst[i] = wp[i];
      P.cin[i] = LCI[i];
      P.cout[i] = LCO[i];
      P.tot[i] = 3 * LCI[i] * LCO[i];
      TOT += P.tot[i];
    }
    k_wpack<<<(TOT + 255) / 256, 256, 0, stream>>>(P, TOT);
  }

  auto plain = [](const float* hf, const bf16* hh, int Ch) {
    VSrc s{hf, hh, nullptr, nullptr, nullptr, 0, Ch, 0}; return s;
  };
  auto upsrc = [](const float* hf, const bf16* hh, const float* skf, const bf16* skh,
                  const int* u, int nprev, int Ch, int Cs) {
    VSrc s{hf, hh, skf, skh, u, nprev, Ch, Cs}; return s;
  };

  // big layer: flat prop + prop2 + streaming combine (ROWS=8, CW=1)
  auto big = [&](const bf16* Xh, VSrc s, float* OUT, bf16* OUTh, int lvl, int n, int Cin,
                 int Cout, const float* Wq, const float* Bp, int smax) {
    int nb = ep.nbase[lvl];
    int t4 = n * (Cin >> 2);
    k_prop_flat<<<(t4 + 255) / 256, 256, 0, stream>>>(Xh, t1f, t1h, cnt, ell, nb, n, Cin);
    k_prop2<<<(t4 + 255) / 256, 256, 0, stream>>>(s, t1h, t2f, cnt, ell, nb, n, Cin);
    int grid = ((Cout + 63) / 64) * ((n + 7) / 8);
    if (smax)
      k_combine<8, 1, 1, 0><<<grid, 256, 0, stream>>>(s, t1f, t1h, t2f, (const float4*)Wq, Bp, cnt, ell, nb, n, Cin, Cout, 0, OUT, OUTh);
    else
      k_combine<8, 1, 0, 0><<<grid, 256, 0, stream>>>(s, t1f, t1h, t2f, (const float4*)Wq, Bp, cnt, ell, nb, n, Cin, Cout, 1, OUT, OUTh);
  };

  // mid layer: virtual prop + gather-combine with per-layer template choice
#define MID(RS, CWv, s, OUT, OUTh, lvl, n, Cin, Cout, Wq, Bp)                                   \
  {                                                                                             \
    int nb = ep.nbase[lvl];                                                                     \
    int t2n = (n) * ((Cin) >> 1);                                                               \
    k_prop_v<<<(t2n + 255) / 256, 256, 0, stream>>>(s, t1f, t1h, cnt, ell, nb, n, Cin);         \
    int grid = (((Cout) + 63) / 64) * (((n) + (RS)-1) / (RS));                                  \
    k_combine<RS, CWv, 0, 1><<<grid, 256, 0, stream>>>(s, t1f, t1h, nullptr, (const float4*)Wq, \
                                                       Bp, cnt, ell, nb, n, Cin, Cout, 1, OUT, OUTh); \
  }

  // ---- L1: n=40962, 4->32 ----
  big(x0h, plain(x0f, x0h, 4), af[0], ah[0], 5, 40962, 4, 32, wp[0], Bb[0], 0);
  // ---- L2: n=10242, 32->64 ----
  big(ah[0], plain(af[0], ah[0], 32), af[1], ah[1], 4, 10242, 32, 64, wp[1], Bb[1], 0);
  // ---- mid encoder ----
  MID(4, 1, plain(af[1], ah[1], 64), af[2], ah[2], 3, 2562, 64, 128, wp[2], Bb[2]);
  MID(2, 2, plain(af[2], ah[2], 128), af[3], ah[3], 2, 642, 128, 256, wp[3], Bb[3]);
  MID(2, 4, plain(af[3], ah[3], 256), af[4], ah[4], 1, 162, 256, 512, wp[4], Bb[4]);
  MID(2, 4, plain(af[4], ah[4], 512), af[5], ah[5], 0, 42, 512, 512, wp[5], Bb[5]);
  // ---- mid decoder ----
  MID(2, 4, upsrc(af[5], ah[5], af[3], ah[3], up[0], 42, 512, 256), af[6], ah[6], 1, 162, 768, 256, wp[6], Bb[6]);
  MID(2, 4, upsrc(af[6], ah[6], af[2], ah[2], up[1], 162, 256, 128), af[7], ah[7], 2, 642, 384, 128, wp[7], Bb[7]);
  MID(2, 4, upsrc(af[7], ah[7], af[1], ah[1], up[2], 642, 128, 64), af[8], ah[8], 3, 2562, 192, 64, wp[8], Bb[8]);
  // ---- L10: n=10242, [64|32]->32 ----
  {
    VSrc s = upsrc(af[8], ah[8], af[0], ah[0], up[3], 2562, 64, 32);
    k_xmat<<<(10242 * 48 + 255) / 256, 256, 0, stream>>>(s, xh, 10242, 96);
    big(xh, s, af[9], ah[9], 4, 10242, 96, 32, wp[9], Bb[9], 0);
  }
  // ---- L11: n=40962, [32|4]->37 + softmax ----
  {
    VSrc s = upsrc(af[9], ah[9], x0f, x0h, up[4], 10242, 32, 4);
    k_xmat<<<(40962 * 18 + 255) / 256, 256, 0, stream>>>(s, xh, 40962, 36);
    big(xh, s, (float*)d_out, nullptr, 5, 40962, 36, 37, wp[10], Bb[10], 1);
  }
}